// Round 4
// baseline (147.516 us; speedup 1.0000x reference)
//
#include <hip/hip_runtime.h>
#include <hip/hip_bf16.h>

typedef __attribute__((ext_vector_type(8))) __bf16 bf16x8;
typedef __attribute__((ext_vector_type(4))) __bf16 bf16x4;
typedef __attribute__((ext_vector_type(4))) float  f32x4;

#define MFMA16(a, b, c) __builtin_amdgcn_mfma_f32_16x16x32_bf16((a), (b), (c), 0, 0, 0)

// B=2, S=4096, D=256, P=R=64. Flattened rows g = b*4096 + n (8192 total).
static constexpr size_t OFF_XB   = 0;                        // bf16 [8192][256]   4 MiB
static constexpr size_t OFF_WVT  = 4u << 20;                 // bf16 [256][256] ([n][k])
static constexpr size_t OFF_WLT  = OFF_WVT + 256 * 256 * 2;  // bf16 [64][256]
static constexpr size_t OFF_WRT  = OFF_WLT + 64 * 256 * 2;   // bf16 [64][256]
static constexpr size_t OFF_WOT  = OFF_WRT + 64 * 256 * 2;   // bf16 [256][256]
static constexpr size_t OFF_VT   = 5u << 20;                 // bf16 [2][64][8][256][8] packed V 4 MiB
static constexpr size_t OFF_L    = 9u << 20;                 // f32  [8192][64]    2 MiB
static constexpr size_t OFF_R    = 11u << 20;                // f32  [8192][64]    2 MiB
static constexpr size_t OFF_PART = 17u << 20;                // bf16 [8][8192][256] 32 MiB
static constexpr size_t OFF_ZP   = 49u << 20;                // f32  [8][8192]     256 KiB

__device__ __forceinline__ void load_lds16(const __bf16* g, __bf16* l) {
  __builtin_amdgcn_global_load_lds((__attribute__((address_space(1))) void*)g,
                                   (__attribute__((address_space(3))) void*)l, 16, 0, 0);
}

__device__ __forceinline__ float fast_exp2(float x) {
  float e;
  asm("v_exp_f32 %0, %1" : "=v"(e) : "v"(x));   // plain VALU trans op, HW-interlocked
  return e;
}

// ------------------------------------------- x -> bf16  +  weight transpose
__global__ __launch_bounds__(256) void k_prep(const float* __restrict__ x,
                                              const float* __restrict__ Wv,
                                              const float* __restrict__ Wl,
                                              const float* __restrict__ Wr,
                                              const float* __restrict__ Wo,
                                              __bf16* __restrict__ xb,
                                              __bf16* __restrict__ Wvt,
                                              __bf16* __restrict__ Wlt,
                                              __bf16* __restrict__ Wrt,
                                              __bf16* __restrict__ Wot) {
  const int bx = blockIdx.x, t = threadIdx.x;
  if (bx < 2048) {
    const int i = (bx * 256 + t) * 4;
    const float4 v = *(const float4*)(x + i);
    bf16x4 o;
    o.x = (__bf16)v.x; o.y = (__bf16)v.y; o.z = (__bf16)v.z; o.w = (__bf16)v.w;
    *(bf16x4*)(xb + i) = o;
    return;
  }
  const int idx = (bx - 2048) * 256 + t;
  if (idx < 65536) {
    const int k = idx >> 8, n = idx & 255;
    Wvt[n * 256 + k] = (__bf16)Wv[idx];
  } else if (idx < 81920) {
    const int j = idx - 65536;
    const int k = j >> 6, n = j & 63;
    Wlt[n * 256 + k] = (__bf16)Wl[j];
  } else if (idx < 98304) {
    const int j = idx - 81920;
    const int k = j >> 6, n = j & 63;
    Wrt[n * 256 + k] = (__bf16)Wr[j];
  } else {
    const int j = idx - 98304;
    const int k = j >> 8, n = j & 255;
    Wot[n * 256 + k] = (__bf16)Wo[j];
  }
}

// --------- projections: V packed [bat][mc][m8][d][j] (bf16), l, r (fp32)
// grid (128, 6): x = 64-row block; y: 0..3 Wv d-tiles, 4 -> Wl, 5 -> Wr
__global__ __launch_bounds__(256) void k_proj(const __bf16* __restrict__ xb,
                                              const __bf16* __restrict__ Wvt,
                                              const __bf16* __restrict__ Wlt,
                                              const __bf16* __restrict__ Wrt,
                                              __bf16* __restrict__ Vt,
                                              float* __restrict__ lbuf,
                                              float* __restrict__ rbuf) {
  __shared__ __align__(16) __bf16 vs[8 * 64 * 8];  // [m8][d_local][j]
  const int t = threadIdx.x;
  const int lane = t & 63, wave = t >> 6;
  const int l16 = lane & 15, quad = lane >> 4;
  const int wr = wave >> 1, wc = wave & 1;
  const int rbk = blockIdx.x;
  const int ct  = blockIdx.y;
  const __bf16* Wt;
  int colbase;
  if (ct < 4)       { Wt = Wvt; colbase = ct * 64; }
  else if (ct == 4) { Wt = Wlt; colbase = 0; }
  else              { Wt = Wrt; colbase = 0; }
  const int row0 = rbk * 64 + wr * 32;
  const int c0   = colbase + wc * 32;
  f32x4 acc[2][2] = {};
  for (int kk = 0; kk < 256; kk += 32) {
    const int ko = kk + quad * 8;
    bf16x8 a0 = *(const bf16x8*)(xb + (size_t)(row0 + l16) * 256 + ko);
    bf16x8 a1 = *(const bf16x8*)(xb + (size_t)(row0 + 16 + l16) * 256 + ko);
    bf16x8 b0 = *(const bf16x8*)(Wt + (size_t)(c0 + l16) * 256 + ko);
    bf16x8 b1 = *(const bf16x8*)(Wt + (size_t)(c0 + 16 + l16) * 256 + ko);
    acc[0][0] = MFMA16(a0, b0, acc[0][0]);
    acc[0][1] = MFMA16(a0, b1, acc[0][1]);
    acc[1][0] = MFMA16(a1, b0, acc[1][0]);
    acc[1][1] = MFMA16(a1, b1, acc[1][1]);
  }
  if (ct < 4) {
#pragma unroll
    for (int mt = 0; mt < 2; ++mt)
#pragma unroll
      for (int nt = 0; nt < 2; ++nt) {
        const int m8 = wr * 4 + mt * 2 + (quad >> 1);
        const int d  = wc * 32 + nt * 16 + l16;
        bf16x4 o;
        o.x = (__bf16)acc[mt][nt][0];
        o.y = (__bf16)acc[mt][nt][1];
        o.z = (__bf16)acc[mt][nt][2];
        o.w = (__bf16)acc[mt][nt][3];
        *(bf16x4*)(&vs[m8 * 512 + d * 8 + (quad & 1) * 4]) = o;
      }
    __syncthreads();
    const int m8 = t >> 5, s32 = t & 31;
    const int bat = rbk >> 6, mc = rbk & 63;
    bf16x8 a = *(const bf16x8*)(&vs[m8 * 512 + s32 * 16]);
    bf16x8 b = *(const bf16x8*)(&vs[m8 * 512 + s32 * 16 + 8]);
    __bf16* dst = Vt + (size_t)bat * 1048576 + (size_t)mc * 16384 +
                  m8 * 2048 + ct * 512 + s32 * 16;
    *(bf16x8*)dst       = a;
    *(bf16x8*)(dst + 8) = b;
  } else {
    float* dstb = (ct == 4) ? lbuf : rbuf;
#pragma unroll
    for (int mt = 0; mt < 2; ++mt)
#pragma unroll
      for (int nt = 0; nt < 2; ++nt) {
        const int col = c0 + nt * 16 + l16;
        const int gr  = rbk * 64 + wr * 32 + mt * 16 + quad * 4;
#pragma unroll
        for (int rr = 0; rr < 4; ++rr)
          dstb[(size_t)(gr + rr) * 64 + col] = acc[mt][nt][rr];
      }
  }
}

// ---------------- fused attention GEMM: pipelined register P-gen, split-K=8
// grid (64, 8). 4 waves: 2 row-waves (64 rows) x 2 col-waves (128 cols).
__global__ __launch_bounds__(256, 2) void k_attn(const float* __restrict__ lbuf,
                                                 const float* __restrict__ rbuf,
                                                 const __bf16* __restrict__ Vt,
                                                 __bf16* __restrict__ part,
                                                 float* __restrict__ zpart) {
  __shared__ __align__(16) char smem[70144];  // vt0 32K | vt1 32K | ls 4.6K ; epi ctile reuses 66.6K
  __bf16* vt0 = (__bf16*)smem;
  __bf16* vt1 = (__bf16*)(smem + 32768);
  float*  ls  = (float*)(smem + 65536);       // [128][9] l-tile (8 used cols + pad)
  const int t = threadIdx.x;
  const int lane = t & 63, w = t >> 6;
  const int l16 = lane & 15, quad = lane >> 4;
  const int wr = w >> 1, wc = w & 1;
  const int rb = blockIdx.x;   // 0..63
  const int sp = blockIdx.y;   // 0..7
  const int g0 = rb * 128;
  const int bat = rb >> 5;
  const int row0 = g0 + wr * 64;
  const __bf16* Vbase = Vt + (size_t)bat * 1048576;

  // l tile: rows g0..+127, cols sp*8..+8
  {
    const int rl = t >> 1, half = t & 1;
    f32x4 v = *(const f32x4*)(lbuf + (size_t)(g0 + rl) * 64 + sp * 8 + half * 4);
#pragma unroll
    for (int i = 0; i < 4; ++i) ls[rl * 9 + half * 4 + i] = v[i];
  }
  // r frags pre-scaled by log2(e)
  const float LOG2E = 1.44269504088896f;
  float rreg[4][16];
#pragma unroll
  for (int mt = 0; mt < 4; ++mt) {
    const float* rp = rbuf + (size_t)(row0 + mt * 16 + l16) * 64;
#pragma unroll
    for (int kk = 0; kk < 2; ++kk) {
      f32x4 a = *(const f32x4*)(rp + kk * 32 + quad * 8);
      f32x4 b = *(const f32x4*)(rp + kk * 32 + quad * 8 + 4);
#pragma unroll
      for (int j = 0; j < 4; ++j) {
        rreg[mt][kk * 8 + j]     = a[j] * LOG2E;
        rreg[mt][kk * 8 + 4 + j] = b[j] * LOG2E;
      }
    }
  }

  f32x4 acc[4][8] = {};
  float zacc[4] = {0.f, 0.f, 0.f, 0.f};
  bf16x8 af[4][2];

  // stage chunk 0 into vt0
  {
    const __bf16* g = Vbase + (size_t)(sp * 8) * 16384;
#pragma unroll
    for (int i = 0; i < 8; ++i)
      load_lds16(g + (size_t)(i * 256 + w * 64 + lane) * 8, vt0 + (i * 256 + w * 64) * 8);
  }
  __syncthreads();

  // A-fragments for chunk 0 (register-only after ls read)
#pragma unroll
  for (int mt = 0; mt < 4; ++mt) {
    const float lv = ls[(wr * 64 + mt * 16 + l16) * 9 + 0];
#pragma unroll
    for (int kk = 0; kk < 2; ++kk)
#pragma unroll
      for (int j = 0; j < 8; ++j) {
        const float e = fast_exp2(lv * rreg[mt][kk * 8 + j]);
        zacc[mt] += e;
        af[mt][kk][j] = (__bf16)e;
      }
  }

  for (int kc = 0; kc < 8; ++kc) {
    __bf16* cur = (kc & 1) ? vt1 : vt0;
    __bf16* nxt = (kc & 1) ? vt0 : vt1;
    float lvn[4];
    if (kc < 7) {
      const __bf16* g = Vbase + (size_t)(sp * 8 + kc + 1) * 16384;
#pragma unroll
      for (int i = 0; i < 8; ++i)
        load_lds16(g + (size_t)(i * 256 + w * 64 + lane) * 8, nxt + (i * 256 + w * 64) * 8);
      // prefetch next chunk's l values (latency hides behind MFMA phase)
#pragma unroll
      for (int mt = 0; mt < 4; ++mt)
        lvn[mt] = ls[(wr * 64 + mt * 16 + l16) * 9 + kc + 1];
    }
    // MFMA phase over current chunk (af already in registers)
#pragma unroll
    for (int kk = 0; kk < 2; ++kk) {
#pragma unroll
      for (int nt = 0; nt < 8; ++nt) {
        bf16x8 bv = *(const bf16x8*)(cur + (kk * 4 + quad) * 2048 +
                                     (wc * 128 + nt * 16 + l16) * 8);
        acc[0][nt] = MFMA16(af[0][kk], bv, acc[0][nt]);
        acc[1][nt] = MFMA16(af[1][kk], bv, acc[1][nt]);
        acc[2][nt] = MFMA16(af[2][kk], bv, acc[2][nt]);
        acc[3][nt] = MFMA16(af[3][kk], bv, acc[3][nt]);
      }
    }
    // generate A-fragments for next chunk (register-only; overlaps MFMA drain)
    if (kc < 7) {
#pragma unroll
      for (int mt = 0; mt < 4; ++mt) {
        const float lv = lvn[mt];
#pragma unroll
        for (int kk = 0; kk < 2; ++kk)
#pragma unroll
          for (int j = 0; j < 8; ++j) {
            const float e = fast_exp2(lv * rreg[mt][kk * 8 + j]);
            zacc[mt] += e;
            af[mt][kk][j] = (__bf16)e;
          }
      }
    }
    __syncthreads();
  }

  // Z partials: reduce over quads
#pragma unroll
  for (int mt = 0; mt < 4; ++mt) {
    float z = zacc[mt];
    z += __shfl_xor(z, 16);
    z += __shfl_xor(z, 32);
    if (wc == 0 && quad == 0)
      zpart[(size_t)sp * 8192 + row0 + mt * 16 + l16] = z;
  }

  // epilogue: stage C tile to LDS (stride 260), then coalesced bf16x8 writes
  __bf16* ctile = (__bf16*)smem;
#pragma unroll
  for (int mt = 0; mt < 4; ++mt)
#pragma unroll
    for (int nt = 0; nt < 8; ++nt) {
      const int r0 = wr * 64 + mt * 16 + quad * 4;
      const int c  = wc * 128 + nt * 16 + l16;
#pragma unroll
      for (int rr = 0; rr < 4; ++rr)
        ctile[(r0 + rr) * 260 + c] = (__bf16)acc[mt][nt][rr];
    }
  __syncthreads();
#pragma unroll
  for (int p = 0; p < 16; ++p) {
    const int idx = p * 256 + t;
    const int row = idx >> 5, seg = idx & 31;
    bf16x8 v = *(const bf16x8*)(ctile + row * 260 + seg * 8);
    *(bf16x8*)(part + (size_t)sp * (8192 * 256) + (size_t)(g0 + row) * 256 + seg * 8) = v;
  }
}

// ------- fused fixup + output GEMM: out = ((sum_s part[s]) / Z) @ Wo (fp32)
// grid (256): 32-row blocks x 256 cols. 4 waves 2x2 (16 rows x 128 cols each).
// No LDS, no barriers: A-frags built in registers from partials, B from L2 Wot.
__global__ __launch_bounds__(256) void k_outfix(const __bf16* __restrict__ part,
                                                const float* __restrict__ zpart,
                                                const __bf16* __restrict__ Wot,
                                                float* __restrict__ out) {
  const int t = threadIdx.x;
  const int lane = t & 63, w = t >> 6;
  const int l16 = lane & 15, quad = lane >> 4;
  const int wr = w >> 1, wc = w & 1;
  const int rb = blockIdx.x;
  const int arow = rb * 32 + wr * 16 + l16;   // A-fragment row for this lane
  float z = 0.f;
#pragma unroll
  for (int s = 0; s < 8; ++s) z += zpart[(size_t)s * 8192 + arow];
  const float iz = 1.0f / z;
  f32x4 acc[8] = {};
#pragma unroll 2
  for (int ks = 0; ks < 8; ++ks) {
    const int k0 = ks * 32 + quad * 8;
    float sum[8] = {};
#pragma unroll
    for (int s = 0; s < 8; ++s) {
      bf16x8 p = *(const bf16x8*)(part + (size_t)s * (8192 * 256) + (size_t)arow * 256 + k0);
#pragma unroll
      for (int j = 0; j < 8; ++j) sum[j] += (float)p[j];
    }
    bf16x8 afr;
#pragma unroll
    for (int j = 0; j < 8; ++j) afr[j] = (__bf16)(sum[j] * iz);
#pragma unroll
    for (int nt = 0; nt < 8; ++nt) {
      bf16x8 bv = *(const bf16x8*)(Wot + (size_t)(wc * 128 + nt * 16 + l16) * 256 + k0);
      acc[nt] = MFMA16(afr, bv, acc[nt]);
    }
  }
#pragma unroll
  for (int nt = 0; nt < 8; ++nt) {
    const int col = wc * 128 + nt * 16 + l16;
    const int r0  = rb * 32 + wr * 16 + quad * 4;
#pragma unroll
    for (int rr = 0; rr < 4; ++rr)
      out[(size_t)(r0 + rr) * 256 + col] = acc[nt][rr];
  }
}

extern "C" void kernel_launch(void* const* d_in, const int* in_sizes, int n_in,
                              void* d_out, int out_size, void* d_ws, size_t ws_size,
                              hipStream_t stream) {
  const float* x  = (const float*)d_in[0];
  const float* Wl = (const float*)d_in[1];
  const float* Wr = (const float*)d_in[2];
  const float* Wv = (const float*)d_in[3];
  const float* Wo = (const float*)d_in[4];
  char* ws = (char*)d_ws;
  __bf16* xb   = (__bf16*)(ws + OFF_XB);
  __bf16* Wvt  = (__bf16*)(ws + OFF_WVT);
  __bf16* Wlt  = (__bf16*)(ws + OFF_WLT);
  __bf16* Wrt  = (__bf16*)(ws + OFF_WRT);
  __bf16* Wot  = (__bf16*)(ws + OFF_WOT);
  __bf16* Vt   = (__bf16*)(ws + OFF_VT);
  float*  lb   = (float*)(ws + OFF_L);
  float*  rbf  = (float*)(ws + OFF_R);
  __bf16* prt  = (__bf16*)(ws + OFF_PART);
  float*  zp   = (float*)(ws + OFF_ZP);
  float*  out  = (float*)d_out;

  k_prep<<<2688, 256, 0, stream>>>(x, Wv, Wl, Wr, Wo, xb, Wvt, Wlt, Wrt, Wot);
  k_proj<<<dim3(128, 6), 256, 0, stream>>>(xb, Wvt, Wlt, Wrt, Vt, lb, rbf);
  k_attn<<<dim3(64, 8), 256, 0, stream>>>(lb, rbf, Vt, prt, zp);
  k_outfix<<<256, 256, 0, stream>>>(prt, zp, Wot, out);
}